// Round 4
// baseline (313.573 us; speedup 1.0000x reference)
//
#include <hip/hip_runtime.h>
#include <math.h>

#define LROWS 16384
#define HDIM  1024
#define MDIM  2048
#define RSQRT_D 0.08838834764831844f   // 1/sqrt(128)

// ---- workspace layout (float offsets) ----
#define OFF_W     0          // w[8][2048]   (zeroed, atomic accum)
#define OFF_BETA  16384      // beta[8]      (zeroed, atomic accum)
#define OFF_Z     16392      // Z[8]         (zeroed, atomic accum)
#define OFF_Q     16400      // q[1024]
#define OFF_FEAT  17424      // feat[1024]
#define OFF_Y     18448      // y[8][2048]   (written by k4c)
#define OFF_YBUF  34832      // ybuf[512][8][2048]  (33.6 MB, written by k35)
// memset zeroes only [0, OFF_Q) = 65.6 KB

__device__ __forceinline__ float dot4(float4 a, float4 b) {
  return a.x * b.x + a.y * b.y + a.z * b.z + a.w * b.w;
}
__device__ __forceinline__ void fma4(float4& acc, float s, float4 v) {
  acc.x = fmaf(s, v.x, acc.x); acc.y = fmaf(s, v.y, acc.y);
  acc.z = fmaf(s, v.z, acc.z); acc.w = fmaf(s, v.w, acc.w);
}
__device__ __forceinline__ void add4(float4& a, float4 v) {
  a.x += v.x; a.y += v.y; a.z += v.z; a.w += v.w;
}

// K1: q[j] = x . Wq[j,:] + bq[j];  beta[j&7] += q[j]*bk[j]   (wave per output)
__global__ __launch_bounds__(256) void k1_q(const float* __restrict__ x,
                                            const float* __restrict__ Wq,
                                            const float* __restrict__ bq,
                                            const float* __restrict__ bk,
                                            float* __restrict__ ws) {
  int tid = threadIdx.x, lane = tid & 63;
  int j = blockIdx.x * 4 + (tid >> 6);
  const float4* xr = (const float4*)x;
  const float4* wr = (const float4*)(Wq + (size_t)j * HDIM);
  float acc = 0.f;
#pragma unroll
  for (int i = 0; i < 4; ++i) {
    int idx = i * 64 + lane;
    acc += dot4(xr[idx], wr[idx]);
  }
#pragma unroll
  for (int off = 32; off; off >>= 1) acc += __shfl_xor(acc, off);
  if (lane == 0) {
    float qj = acc + bq[j];
    ws[OFF_Q + j] = qj;
    atomicAdd(&ws[OFF_BETA + (j & 7)], qj * bk[j]);
  }
}

// K2: w[n][m] = sum_{c: c%8==n} q[c] * Wk[c][m]   (c-chunked, atomic accum)
// grid 256 = 8 m-chunks x 32 c-chunks (32 channels each)
__global__ __launch_bounds__(256) void k2_w(const float* __restrict__ Wk,
                                            float* __restrict__ ws) {
  int tid = threadIdx.x;
  int mc = blockIdx.x & 7, cc = blockIdx.x >> 3;
  int m = mc * 256 + tid;
  const float* q = ws + OFF_Q;
  float acc[8];
#pragma unroll
  for (int n = 0; n < 8; ++n) acc[n] = 0.f;
  int c0 = cc * 32;
  for (int c = c0; c < c0 + 32; c += 8) {
#pragma unroll
    for (int u = 0; u < 8; ++u)
      acc[u] = fmaf(q[c + u], Wk[(size_t)(c + u) * MDIM + m], acc[u]);
  }
#pragma unroll
  for (int n = 0; n < 8; ++n) atomicAdd(&ws[OFF_W + n * MDIM + m], acc[n]);
}

// K35: fused scores + exp + weighted memory sum. One group of 32 rows/block.
// grid 512. Wave owns 8 rows in phase A (acc[8][8]); software-pipelined loads.
__global__ __launch_bounds__(256, 2) void k35(const float* __restrict__ mem,
                                              float* __restrict__ ws) {
  __shared__ float sred[4][32][68];   // 34.8 KB; [wave][lane32][value(+pad)]
  __shared__ float4 pv4[64];          // p[32 rows][8 heads]
  int tid = threadIdx.x, lane = tid & 63, wv = tid >> 6;
  const float* wmat = ws + OFF_W;
  int r0 = blockIdx.x * 32;
  int rw = r0 + wv * 8;

  // ---- phase A: scores, wave = 8 rows ----
  float acc[8][8];
#pragma unroll
  for (int rr = 0; rr < 8; ++rr)
#pragma unroll
    for (int n = 0; n < 8; ++n) acc[rr][n] = 0.f;

  float4 wvv[8];      // single-buffer (L2-hot)
  float4 mv[2][8];    // double-buffer (HBM stream)

  auto loadW = [&](int s) {
    int mq = s * 64 + lane;
#pragma unroll
    for (int n = 0; n < 8; ++n)
      wvv[n] = *(const float4*)(wmat + n * MDIM + mq * 4);
  };
  auto loadM = [&](int s, int b) {
    int mq = s * 64 + lane;
#pragma unroll
    for (int rr = 0; rr < 8; ++rr)
      mv[b][rr] = *(const float4*)(mem + (size_t)(rw + rr) * MDIM + mq * 4);
  };

  loadM(0, 0);
#pragma unroll
  for (int s = 0; s < 8; ++s) {
    int cur = s & 1;
    loadW(s);                          // issued before next-step mv
    if (s < 7) loadM(s + 1, cur ^ 1);  // prefetch: stays in flight during FMAs
#pragma unroll
    for (int rr = 0; rr < 8; ++rr) {
      float4 m = mv[cur][rr];
#pragma unroll
      for (int n = 0; n < 8; ++n) {
        acc[rr][n] = fmaf(m.x, wvv[n].x, acc[rr][n]);
        acc[rr][n] = fmaf(m.y, wvv[n].y, acc[rr][n]);
        acc[rr][n] = fmaf(m.z, wvv[n].z, acc[rr][n]);
        acc[rr][n] = fmaf(m.w, wvv[n].w, acc[rr][n]);
      }
    }
  }
  // pre-reduce lane pairs {l, l^32}; lanes<32 spill 64 values as b128
#pragma unroll
  for (int rr = 0; rr < 8; ++rr)
#pragma unroll
    for (int n = 0; n < 8; ++n) acc[rr][n] += __shfl_xor(acc[rr][n], 32);
  if (lane < 32) {
#pragma unroll
    for (int j = 0; j < 16; ++j) {
      int rr = j >> 1, n0 = (j & 1) * 4;
      *(float4*)&sred[wv][lane][j * 4] =
          make_float4(acc[rr][n0], acc[rr][n0 + 1], acc[rr][n0 + 2], acc[rr][n0 + 3]);
    }
  }
  __syncthreads();

  // ---- reduce + exp: all 256 threads, thread = (row, head) ----
  {
    int row = tid >> 3, n = tid & 7;
    int wvs = row >> 3, v = (row & 7) * 8 + n;
    float ssum = 0.f;
#pragma unroll
    for (int l = 0; l < 32; ++l) ssum += sred[wvs][l][v];
    float sc = (ssum + ws[OFF_BETA + n]) * RSQRT_D;
    float p = __expf(sc);             // no max-shift: |s| provably small
    ((float*)pv4)[tid] = p;
    float z = p;
    z += __shfl_xor(z, 8); z += __shfl_xor(z, 16); z += __shfl_xor(z, 32);
    if (lane < 8) atomicAdd(&ws[OFF_Z + lane], z);
  }
  __syncthreads();

  // ---- phase B: y[n][cols] += p * mem, rows cache-hot; double-buffered ----
  float4 y0[8], y1[8];
#pragma unroll
  for (int n = 0; n < 8; ++n) {
    y0[n] = make_float4(0.f, 0.f, 0.f, 0.f);
    y1[n] = make_float4(0.f, 0.f, 0.f, 0.f);
  }
  float4 mb[2][8];
  auto loadB = [&](int i, int b) {
#pragma unroll
    for (int rr = 0; rr < 4; ++rr) {
      const float* row = mem + (size_t)(r0 + i * 4 + rr) * MDIM;
      mb[b][rr * 2]     = *(const float4*)(row + tid * 4);
      mb[b][rr * 2 + 1] = *(const float4*)(row + 1024 + tid * 4);
    }
  };
  loadB(0, 0);
#pragma unroll
  for (int i = 0; i < 8; ++i) {
    int cur = i & 1;
    if (i < 7) loadB(i + 1, cur ^ 1);
#pragma unroll
    for (int rr = 0; rr < 4; ++rr) {
      int rl = i * 4 + rr;
      float4 pA = pv4[rl * 2];        // LDS broadcast
      float4 pB = pv4[rl * 2 + 1];
      float4 m0 = mb[cur][rr * 2], m1 = mb[cur][rr * 2 + 1];
      fma4(y0[0], pA.x, m0); fma4(y1[0], pA.x, m1);
      fma4(y0[1], pA.y, m0); fma4(y1[1], pA.y, m1);
      fma4(y0[2], pA.z, m0); fma4(y1[2], pA.z, m1);
      fma4(y0[3], pA.w, m0); fma4(y1[3], pA.w, m1);
      fma4(y0[4], pB.x, m0); fma4(y1[4], pB.x, m1);
      fma4(y0[5], pB.y, m0); fma4(y1[5], pB.y, m1);
      fma4(y0[6], pB.z, m0); fma4(y1[6], pB.z, m1);
      fma4(y0[7], pB.w, m0); fma4(y1[7], pB.w, m1);
    }
  }
  // spill block y to private slot (no atomics)
  float* yb = ws + OFF_YBUF + (size_t)blockIdx.x * 16384;
#pragma unroll
  for (int n = 0; n < 8; ++n) {
    *(float4*)(yb + n * MDIM + tid * 4) = y0[n];
    *(float4*)(yb + n * MDIM + 1024 + tid * 4) = y1[n];
  }
}

// K4c: y[q] = sum_{b=0..511} ybuf[b][q]   (q = float4 index, 4096 total)
__global__ __launch_bounds__(256) void k4c(float* __restrict__ ws) {
  __shared__ float4 sA[256];
  int t = threadIdx.x;
  int quad = blockIdx.x * 16 + (t & 15);
  int b0 = (t >> 4) * 32;
  const float4* src = (const float4*)(ws + OFF_YBUF);
  float4 acc = make_float4(0.f, 0.f, 0.f, 0.f);
  for (int b = b0; b < b0 + 32; ++b)
    add4(acc, src[(size_t)b * 4096 + quad]);
  sA[(t & 15) * 16 + (t >> 4)] = acc;
  __syncthreads();
  if (t < 16) {
    float4 s = sA[t * 16];
#pragma unroll
    for (int j = 1; j < 16; ++j) add4(s, sA[t * 16 + j]);
    ((float4*)(ws + OFF_Y))[blockIdx.x * 16 + t] = s;
  }
}

// K6: feat[c] = (y[c&7] . Wv[c,:]) / Z[c&7] + bv[c]   (wave per c)
__global__ __launch_bounds__(256) void k6_feat(const float* __restrict__ Wv,
                                               const float* __restrict__ bv,
                                               float* __restrict__ ws) {
  int tid = threadIdx.x, lane = tid & 63;
  int c = blockIdx.x * 4 + (tid >> 6);
  int n = c & 7;
  const float4* yb = (const float4*)(ws + OFF_Y + n * MDIM);
  const float4* wb = (const float4*)(Wv + (size_t)c * MDIM);
  float acc = 0.f;
#pragma unroll
  for (int s = 0; s < 8; ++s) {
    int idx = s * 64 + lane;
    acc += dot4(yb[idx], wb[idx]);
  }
#pragma unroll
  for (int off = 32; off; off >>= 1) acc += __shfl_xor(acc, off);
  if (lane == 0) ws[OFF_FEAT + c] = acc / ws[OFF_Z + n] + bv[c];
}

// K7: out[j] = relu(x . Wo[j,0:1024] + feat . Wo[j,1024:2048] + bo[j]) (wave per j)
__global__ __launch_bounds__(256) void k7_out(const float* __restrict__ x,
                                              const float* __restrict__ Wo,
                                              const float* __restrict__ bo,
                                              const float* __restrict__ ws,
                                              float* __restrict__ out) {
  int tid = threadIdx.x, lane = tid & 63;
  int j = blockIdx.x * 4 + (tid >> 6);
  const float4* wb = (const float4*)(Wo + (size_t)j * 2048);
  const float4* xr = (const float4*)x;
  const float4* fr = (const float4*)(ws + OFF_FEAT);
  float acc = 0.f;
#pragma unroll
  for (int s = 0; s < 4; ++s) {
    int idx = s * 64 + lane;
    acc += dot4(xr[idx], wb[idx]);
    acc += dot4(fr[idx], wb[256 + idx]);
  }
#pragma unroll
  for (int off = 32; off; off >>= 1) acc += __shfl_xor(acc, off);
  if (lane == 0) out[j] = fmaxf(acc + bo[j], 0.f);
}

extern "C" void kernel_launch(void* const* d_in, const int* in_sizes, int n_in,
                              void* d_out, int out_size, void* d_ws, size_t ws_size,
                              hipStream_t stream) {
  const float* x   = (const float*)d_in[0];
  const float* mem = (const float*)d_in[1];
  const float* Wq  = (const float*)d_in[2];
  const float* bq  = (const float*)d_in[3];
  const float* Wk  = (const float*)d_in[4];
  const float* bk  = (const float*)d_in[5];
  const float* Wv  = (const float*)d_in[6];
  const float* bv  = (const float*)d_in[7];
  const float* Wo  = (const float*)d_in[8];
  const float* bo  = (const float*)d_in[9];
  float* ws  = (float*)d_ws;
  float* out = (float*)d_out;

  // zero w, beta, Z (65.6 KB)
  hipMemsetAsync(ws, 0, OFF_Q * sizeof(float), stream);

  k1_q   <<<256, 256, 0, stream>>>(x, Wq, bq, bk, ws);
  k2_w   <<<256, 256, 0, stream>>>(Wk, ws);
  k35    <<<512, 256, 0, stream>>>(mem, ws);
  k4c    <<<256, 256, 0, stream>>>(ws);
  k6_feat<<<256, 256, 0, stream>>>(Wv, bv, ws);
  k7_out <<<256, 256, 0, stream>>>(x, Wo, bo, ws, out);
}